// Round 1
// baseline (226.156 us; speedup 1.0000x reference)
//
#include <hip/hip_runtime.h>

#define EPS 1e-6f
#define LN2 0.6931471805599453f

typedef float f4 __attribute__((ext_vector_type(4)));

constexpr int B = 64;
constexpr int NPB = 512 * 512;                     // elements per batch = 262144
constexpr int BLOCKS_PER_BATCH = 16;
constexpr int NBLK = B * BLOCKS_PER_BATCH;         // 1024 blocks = 4/CU
constexpr int THREADS = 256;
constexpr int CHUNK = NPB / BLOCKS_PER_BATCH;      // 16384 elements per block
constexpr int ITERS = CHUNK / 4 / THREADS;         // 16 float4-pairs per thread

__device__ __forceinline__ float waveReduce(float v) {
    #pragma unroll
    for (int off = 32; off > 0; off >>= 1) v += __shfl_down(v, off, 64);
    return v;
}

// Fused kernel: per-block partials (Sp, St, S2 = sum (t+e)*(log2(t+e)-log2(p+e)))
// + ticket-based last-block finalize (replaces the serialized 1-block kl_final
// launch: saves launch gap + tiny-kernel exec, ~4-8 us).
// Hot loop unchanged from the proven 136.5us kernel: nt loads (L3-retention
// bypass; harness re-poisons a 256MiB ws each iter, flushing L3 anyway) +
// depth-2 rotating register pipeline keeping one load-pair in flight under
// every compute phase.
__global__ __launch_bounds__(THREADS) void kl_fused(
        const float* __restrict__ pred, const float* __restrict__ truem,
        float* __restrict__ ws, unsigned int* __restrict__ ticket,
        float* __restrict__ out) {
    const size_t base = (size_t)blockIdx.x * CHUNK;
    const f4* p4 = (const f4*)(pred + base);
    const f4* t4 = (const f4*)(truem + base);

    float sp = 0.f, st = 0.f, s = 0.f;

    f4 pc = __builtin_nontemporal_load(&p4[threadIdx.x]);
    f4 tc = __builtin_nontemporal_load(&t4[threadIdx.x]);
    #pragma unroll
    for (int j = 1; j <= ITERS; ++j) {
        f4 pn, tn;
        if (j < ITERS) {
            pn = __builtin_nontemporal_load(&p4[threadIdx.x + j * THREADS]);
            tn = __builtin_nontemporal_load(&t4[threadIdx.x + j * THREADS]);
        }
        // consume cur while next is in flight
        sp += (pc.x + pc.y) + (pc.z + pc.w);
        st += (tc.x + tc.y) + (tc.z + tc.w);
        float px = pc.x + EPS, py = pc.y + EPS, pz = pc.z + EPS, pw = pc.w + EPS;
        float tx = tc.x + EPS, ty = tc.y + EPS, tz = tc.z + EPS, tw = tc.w + EPS;
        s += tx * (__log2f(tx) - __log2f(px));
        s += ty * (__log2f(ty) - __log2f(py));
        s += tz * (__log2f(tz) - __log2f(pz));
        s += tw * (__log2f(tw) - __log2f(pw));
        pc = pn; tc = tn;
    }

    sp = waveReduce(sp);
    st = waveReduce(st);
    s  = waveReduce(s);

    __shared__ float red[3][THREADS / 64];
    __shared__ int sh_last;
    const int wave = threadIdx.x >> 6;
    const int lane = threadIdx.x & 63;
    if (lane == 0) { red[0][wave] = sp; red[1][wave] = st; red[2][wave] = s; }
    __syncthreads();
    if (threadIdx.x == 0) {
        float a0 = 0.f, a1 = 0.f, a2 = 0.f;
        #pragma unroll
        for (int w = 0; w < THREADS / 64; ++w) {
            a0 += red[0][w]; a1 += red[1][w]; a2 += red[2][w];
        }
        ws[blockIdx.x]            = a0;   // Sp partial (without eps)
        ws[NBLK + blockIdx.x]     = a1;   // St partial (without eps)
        ws[2 * NBLK + blockIdx.x] = a2;   // S partial, log2 units
        __threadfence();                  // release partials before ticket
        unsigned int t = __hip_atomic_fetch_add(
            ticket, 1u, __ATOMIC_ACQ_REL, __HIP_MEMORY_SCOPE_AGENT);
        sh_last = (t == (unsigned int)(NBLK - 1));
    }
    __syncthreads();
    if (!sh_last) return;

    // ---- last block: finalize (exact summation order of the old kl_final,
    // so the result stays bit-identical: absmax 0.0) ----
    __threadfence();                      // acquire side
    if (threadIdx.x < B) {
        const int b = threadIdx.x;        // one wave, one batch per lane
        float Sp = 0.f, St = 0.f, S = 0.f;
        #pragma unroll
        for (int k = 0; k < BLOCKS_PER_BATCH; ++k) {
            const int idx = b * BLOCKS_PER_BATCH + k;
            Sp += __hip_atomic_load(&ws[idx],
                    __ATOMIC_RELAXED, __HIP_MEMORY_SCOPE_AGENT);
            St += __hip_atomic_load(&ws[NBLK + idx],
                    __ATOMIC_RELAXED, __HIP_MEMORY_SCOPE_AGENT);
            S  += __hip_atomic_load(&ws[2 * NBLK + idx],
                    __ATOMIC_RELAXED, __HIP_MEMORY_SCOPE_AGENT);
        }
        const float epsN = (float)NPB * EPS;   // sum of the per-element +EPS
        Sp += epsN;
        St += epsN;
        float kl = (S * LN2) / St + logf(Sp / St);
        kl = waveReduce(kl);
        if (b == 0) out[0] = kl * (1.0f / B);
    }
}

extern "C" void kernel_launch(void* const* d_in, const int* in_sizes, int n_in,
                              void* d_out, int out_size, void* d_ws, size_t ws_size,
                              hipStream_t stream) {
    const float* pred  = (const float*)d_in[0];
    const float* truem = (const float*)d_in[1];
    float* out = (float*)d_out;
    float* ws  = (float*)d_ws;
    unsigned int* ticket = (unsigned int*)(ws + 3 * NBLK);

    // ws is re-poisoned by the harness each iteration: ticket must be zeroed.
    // 4-byte stream-ordered memset, graph-capture safe.
    hipMemsetAsync(ticket, 0, sizeof(unsigned int), stream);
    kl_fused<<<NBLK, THREADS, 0, stream>>>(pred, truem, ws, ticket, out);
}

// Round 2
// 138.566 us; speedup vs baseline: 1.6321x; 1.6321x over previous
//
#include <hip/hip_runtime.h>

#define EPS 1e-6f
#define LN2 0.6931471805599453f

typedef float f4 __attribute__((ext_vector_type(4)));

constexpr int B = 64;
constexpr int NPB = 512 * 512;                     // elements per batch = 262144
constexpr int BLOCKS_PER_BATCH = 16;
constexpr int NBLK = B * BLOCKS_PER_BATCH;         // 1024 blocks = 4/CU
constexpr int THREADS = 256;
constexpr int CHUNK = NPB / BLOCKS_PER_BATCH;      // 16384 elements per block
constexpr int ITERS = CHUNK / 4 / THREADS;         // 16 float4-pairs per thread
constexpr int DEPTH = 4;                           // load-pairs in flight per wave

__device__ __forceinline__ float waveReduce(float v) {
    #pragma unroll
    for (int off = 32; off > 0; off >>= 1) v += __shfl_down(v, off, 64);
    return v;
}

// Kernel 1: per-block partials (Sp, St, S2 = sum (t+e)*(log2(t+e)-log2(p+e))).
// nt loads (L3-retention bypass; harness re-poisons 256MiB ws each iter) +
// depth-4 rotating register pipeline: 3 load-pairs in flight per wave under
// every compute phase (round-1 disasm showed the depth-2 source pinned the
// compiler at VGPR=32, i.e. one outstanding pair -> latency-limited stream).
// All buffer indices are compile-time constants after full unroll (no scratch).
//
// NOTE (round-1 lesson): do NOT fuse the finalize via per-block agent-scope
// fence/atomic — on multi-XCD gfx950 each release/acquire emits
// buffer_wbl2/buffer_inv (full L2 writeback/invalidate); 1024 of them cost
// ~+75us and strangle the stream (measured 115us vs <40us for this loop).
__global__ __launch_bounds__(THREADS) void kl_partial(
        const float* __restrict__ pred, const float* __restrict__ truem,
        float* __restrict__ ws) {
    const size_t base = (size_t)blockIdx.x * CHUNK;
    const f4* p4 = (const f4*)(pred + base);
    const f4* t4 = (const f4*)(truem + base);

    float sp = 0.f, st = 0.f, s = 0.f;

    f4 pb[DEPTH], tb[DEPTH];
    #pragma unroll
    for (int j = 0; j < DEPTH - 1; ++j) {
        pb[j] = __builtin_nontemporal_load(&p4[threadIdx.x + j * THREADS]);
        tb[j] = __builtin_nontemporal_load(&t4[threadIdx.x + j * THREADS]);
    }

    #pragma unroll
    for (int j = 0; j < ITERS; ++j) {
        if (j + DEPTH - 1 < ITERS) {
            const int slot = (j + DEPTH - 1) & (DEPTH - 1);
            pb[slot] = __builtin_nontemporal_load(
                &p4[threadIdx.x + (j + DEPTH - 1) * THREADS]);
            tb[slot] = __builtin_nontemporal_load(
                &t4[threadIdx.x + (j + DEPTH - 1) * THREADS]);
        }
        const f4 pc = pb[j & (DEPTH - 1)];
        const f4 tc = tb[j & (DEPTH - 1)];

        // identical arithmetic order to the 136.5us baseline (bit-exact)
        sp += (pc.x + pc.y) + (pc.z + pc.w);
        st += (tc.x + tc.y) + (tc.z + tc.w);
        float px = pc.x + EPS, py = pc.y + EPS, pz = pc.z + EPS, pw = pc.w + EPS;
        float tx = tc.x + EPS, ty = tc.y + EPS, tz = tc.z + EPS, tw = tc.w + EPS;
        s += tx * (__log2f(tx) - __log2f(px));
        s += ty * (__log2f(ty) - __log2f(py));
        s += tz * (__log2f(tz) - __log2f(pz));
        s += tw * (__log2f(tw) - __log2f(pw));
    }

    sp = waveReduce(sp);
    st = waveReduce(st);
    s  = waveReduce(s);

    __shared__ float red[3][THREADS / 64];
    const int wave = threadIdx.x >> 6;
    const int lane = threadIdx.x & 63;
    if (lane == 0) { red[0][wave] = sp; red[1][wave] = st; red[2][wave] = s; }
    __syncthreads();
    if (threadIdx.x == 0) {
        float a0 = 0.f, a1 = 0.f, a2 = 0.f;
        #pragma unroll
        for (int w = 0; w < THREADS / 64; ++w) {
            a0 += red[0][w]; a1 += red[1][w]; a2 += red[2][w];
        }
        ws[blockIdx.x]            = a0;   // Sp partial (without eps)
        ws[NBLK + blockIdx.x]     = a1;   // St partial (without eps)
        ws[2 * NBLK + blockIdx.x] = a2;   // S partial, log2 units
    }
}

// Kernel 2: sum 16 partials per batch, fold eps + ln2, mean over B.
__global__ __launch_bounds__(64) void kl_final(
        const float* __restrict__ ws, float* __restrict__ out) {
    const int b = threadIdx.x;   // one wave, one batch per lane
    float Sp = 0.f, St = 0.f, S = 0.f;
    #pragma unroll
    for (int k = 0; k < BLOCKS_PER_BATCH; ++k) {
        const int idx = b * BLOCKS_PER_BATCH + k;
        Sp += ws[idx];
        St += ws[NBLK + idx];
        S  += ws[2 * NBLK + idx];
    }
    const float epsN = (float)NPB * EPS;   // sum of the per-element +EPS
    Sp += epsN;
    St += epsN;
    float kl = (S * LN2) / St + logf(Sp / St);
    kl = waveReduce(kl);
    if (b == 0) out[0] = kl * (1.0f / B);
}

extern "C" void kernel_launch(void* const* d_in, const int* in_sizes, int n_in,
                              void* d_out, int out_size, void* d_ws, size_t ws_size,
                              hipStream_t stream) {
    const float* pred  = (const float*)d_in[0];
    const float* truem = (const float*)d_in[1];
    float* out = (float*)d_out;
    float* ws  = (float*)d_ws;

    kl_partial<<<NBLK, THREADS, 0, stream>>>(pred, truem, ws);
    kl_final<<<1, 64, 0, stream>>>(ws, out);
}